// Round 6
// baseline (392.954 us; speedup 1.0000x reference)
//
#include <hip/hip_runtime.h>
#include <hip/hip_bf16.h>

#define DIM_IN  128
#define DIM_OUT 64
#define RPB     256     // rows per bucket (bucket = row >> 8)
#define NB_MAX  256     // max buckets (needs n_nodes <= 65536)
#define MS_EPB  4096    // edges per multisplit block (256 thr x 16)
#define RED_THREADS 512

typedef __attribute__((ext_vector_type(8))) short bf16x8;
typedef __attribute__((ext_vector_type(4))) float f32x4;

static inline size_t align256(size_t x) { return (x + 255) & ~(size_t)255; }

static __device__ inline short f2bs(float f) {
    __hip_bfloat16 b = __float2bfloat16(f);
    return *reinterpret_cast<short*>(&b);
}

// ---------------------------------------------------------------------------
// K1: hb = bf16(x @ W) via MFMA 16x16x32 bf16. One wave per 16-row tile.
// W pre-packed once per block into LDS in fragment order [ks][nt][lane][8]
// (16 KB bf16) -> each wave reads its 16 B fragments conflict-free.
// ---------------------------------------------------------------------------
__global__ __launch_bounds__(256) void gnn_gemm_mfma_kernel(
    const float* __restrict__ x, const float* __restrict__ W,
    __hip_bfloat16* __restrict__ hb, int n_nodes)
{
    __shared__ short ldsW[4 * 4 * 64 * 8];   // 16 KiB

    // coalesced W read (consecutive tid -> consecutive col), scattered LDS write
    for (int t = threadIdx.x; t < DIM_IN * DIM_OUT; t += 256) {
        const int k = t >> 6;          // 0..127
        const int c = t & 63;          // 0..63
        const int ks  = k >> 5;        // 0..3
        const int g   = (k >> 3) & 3;  // 0..3
        const int i   = k & 7;         // 0..7
        const int nt  = c >> 4;        // 0..3
        const int l16 = c & 15;        // 0..15
        const int lane = g * 16 + l16;
        ldsW[((ks * 4 + nt) * 64 + lane) * 8 + i] = f2bs(W[k * DIM_OUT + c]);
    }
    __syncthreads();

    const int lane = threadIdx.x & 63;
    const int wid  = blockIdx.x * 4 + (threadIdx.x >> 6);
    const int ntile_rows = (n_nodes + 15) >> 4;
    if (wid >= ntile_rows) return;

    const int g   = lane >> 4;
    const int l16 = lane & 15;

    // A loads first (HBM latency)
    const int row = wid * 16 + l16;
    const int arow = (row < n_nodes) ? row : (n_nodes - 1);
    const float* xr = x + (size_t)arow * DIM_IN + g * 8;
    float4 a_lo[4], a_hi[4];
    #pragma unroll
    for (int ks = 0; ks < 4; ++ks) {
        a_lo[ks] = *reinterpret_cast<const float4*>(xr + ks * 32);
        a_hi[ks] = *reinterpret_cast<const float4*>(xr + ks * 32 + 4);
    }

    // B fragments from LDS (16 B/lane, linear -> conflict-free)
    bf16x8 bfrag[4][4];
    #pragma unroll
    for (int ks = 0; ks < 4; ++ks)
        #pragma unroll
        for (int nt = 0; nt < 4; ++nt)
            bfrag[ks][nt] = *reinterpret_cast<bf16x8*>(
                &ldsW[((ks * 4 + nt) * 64 + lane) * 8]);

    bf16x8 afrag[4];
    #pragma unroll
    for (int ks = 0; ks < 4; ++ks) {
        bf16x8 f;
        f[0] = f2bs(a_lo[ks].x); f[1] = f2bs(a_lo[ks].y);
        f[2] = f2bs(a_lo[ks].z); f[3] = f2bs(a_lo[ks].w);
        f[4] = f2bs(a_hi[ks].x); f[5] = f2bs(a_hi[ks].y);
        f[6] = f2bs(a_hi[ks].z); f[7] = f2bs(a_hi[ks].w);
        afrag[ks] = f;
    }

    f32x4 acc[4] = {{0,0,0,0},{0,0,0,0},{0,0,0,0},{0,0,0,0}};
    #pragma unroll
    for (int ks = 0; ks < 4; ++ks)
        #pragma unroll
        for (int nt = 0; nt < 4; ++nt)
            acc[nt] = __builtin_amdgcn_mfma_f32_16x16x32_bf16(
                afrag[ks], bfrag[ks][nt], acc[nt], 0, 0, 0);

    #pragma unroll
    for (int nt = 0; nt < 4; ++nt)
        #pragma unroll
        for (int r = 0; r < 4; ++r) {
            const int orow = wid * 16 + g * 4 + r;
            if (orow < n_nodes)
                hb[(size_t)orow * DIM_OUT + nt * 16 + l16] =
                    __float2bfloat16(acc[nt][r]);
        }
}

// ---------------------------------------------------------------------------
// K2a: bucket histogram (LDS-staged; few global atomics)
// ---------------------------------------------------------------------------
__global__ __launch_bounds__(256) void gnn_bucket_hist_kernel(
    const int* __restrict__ edge_rows, int* __restrict__ ghist,
    int n_edges, int nb)
{
    __shared__ int lh[NB_MAX];
    for (int i = threadIdx.x; i < nb; i += 256) lh[i] = 0;
    __syncthreads();
    for (int e = blockIdx.x * 256 + threadIdx.x; e < n_edges;
         e += gridDim.x * 256)
        atomicAdd(&lh[((unsigned)edge_rows[e]) >> 8], 1);
    __syncthreads();
    for (int i = threadIdx.x; i < nb; i += 256)
        if (lh[i]) atomicAdd(&ghist[i], lh[i]);
}

// ---------------------------------------------------------------------------
// K2b: exclusive scan of <=256 bucket counts -> goff[nb+1], gcur
// ---------------------------------------------------------------------------
__global__ __launch_bounds__(256) void gnn_bucket_scan_kernel(
    const int* __restrict__ ghist, int* __restrict__ goff,
    int* __restrict__ gcur, int nb, int n_edges)
{
    __shared__ int ws_[4];
    const int tid = threadIdx.x, lane = tid & 63, wv = tid >> 6;
    const int v = (tid < nb) ? ghist[tid] : 0;
    int incl = v;
    #pragma unroll
    for (int off = 1; off < 64; off <<= 1) {
        const int t = __shfl_up(incl, off);
        if (lane >= off) incl += t;
    }
    if (lane == 63) ws_[wv] = incl;
    __syncthreads();
    int wb = 0;
    for (int w = 0; w < wv; ++w) wb += ws_[w];
    if (tid < nb) {
        const int excl = wb + incl - v;
        goff[tid] = excl;
        gcur[tid] = excl;
    }
    if (tid == 0) goff[nb] = n_edges;
}

// ---------------------------------------------------------------------------
// K2c: block-local multisplit into bucket-grouped pairs.
// pair.x = bucket<<24 | row_local<<16 | col (cleared to 24 bits on flush)
// pair.y = adj_val bits. Flush is per-bucket contiguous (~21-pair runs)
// -> near-sequential global writes, no 64B-line amplification.
// ---------------------------------------------------------------------------
__global__ __launch_bounds__(256) void gnn_multisplit_kernel(
    const int* __restrict__ edge_rows, const int* __restrict__ edge_cols,
    const float* __restrict__ adj_vals, int* __restrict__ gcur,
    uint2* __restrict__ pairs, int n_edges, int nb)
{
    __shared__ uint2 pbuf[MS_EPB];     // 32 KiB
    __shared__ int lh[NB_MAX];
    __shared__ int lbase[NB_MAX];
    __shared__ int gbase[NB_MAX];
    __shared__ int wscan[4];

    const int tid  = threadIdx.x;
    const int base = blockIdx.x * MS_EPB;
    const int ecnt = (n_edges - base < MS_EPB) ? (n_edges - base) : MS_EPB;

    for (int i = tid; i < nb; i += 256) lh[i] = 0;
    __syncthreads();

    unsigned w0[16], w1[16];
    const int my0 = base + tid * 16;
    #pragma unroll
    for (int i = 0; i < 16; ++i) {
        const int e = my0 + i;
        if (e < n_edges) {
            const unsigned r = (unsigned)edge_rows[e];
            const unsigned b = r >> 8;
            w0[i] = ((unsigned)edge_cols[e] & 0xFFFFu) | ((r & 255u) << 16) |
                    (b << 24);
            w1[i] = __float_as_uint(adj_vals[e]);
            atomicAdd(&lh[b], 1);
        } else {
            w0[i] = 0xFFFFFFFFu;   // impossible: bucket <= nb-1 < 255
        }
    }
    __syncthreads();

    // block-local exclusive scan of lh -> lbase; claim global chunks
    {
        const int lane = tid & 63, wv = tid >> 6;
        const int v = (tid < nb) ? lh[tid] : 0;
        int incl = v;
        #pragma unroll
        for (int off = 1; off < 64; off <<= 1) {
            const int t = __shfl_up(incl, off);
            if (lane >= off) incl += t;
        }
        if (lane == 63) wscan[wv] = incl;
        __syncthreads();
        int wb = 0;
        for (int w = 0; w < wv; ++w) wb += wscan[w];
        if (tid < nb) {
            lbase[tid] = wb + incl - v;
            gbase[tid] = v ? atomicAdd(&gcur[tid], v) : 0;
        }
    }
    __syncthreads();
    for (int i = tid; i < nb; i += 256) lh[i] = lbase[i];  // reuse as cursor
    __syncthreads();

    #pragma unroll
    for (int i = 0; i < 16; ++i) {
        if (w0[i] != 0xFFFFFFFFu) {
            const int b = w0[i] >> 24;
            const int s = atomicAdd(&lh[b], 1);
            pbuf[s] = make_uint2(w0[i], w1[i]);
        }
    }
    __syncthreads();

    for (int s = tid; s < ecnt; s += 256) {
        const uint2 p = pbuf[s];
        const int b = p.x >> 24;
        pairs[gbase[b] + (s - lbase[b])] = make_uint2(p.x & 0x00FFFFFFu, p.y);
    }
}

// ---------------------------------------------------------------------------
// K3: per-bucket reduce with LDS accumulator (256 rows x 65 padded floats).
// 8 waves x 4 edges in flight; 16 lanes/edge gather 128 B bf16 h rows;
// ds_add_f32 LDS atomics (pad 65 randomizes banks across rows). Each row
// owned by exactly one block -> plain coalesced float4 store, no pre-zero.
// ---------------------------------------------------------------------------
__global__ __launch_bounds__(RED_THREADS) void gnn_reduce_lds_kernel(
    const __hip_bfloat16* __restrict__ hb, const int* __restrict__ goff,
    const uint2* __restrict__ pairs, float* __restrict__ out, int n_nodes)
{
    __shared__ float acc[RPB * 65];    // 66560 B
    const int tid = threadIdx.x;
    for (int i = tid; i < RPB * 65; i += RED_THREADS) acc[i] = 0.f;
    __syncthreads();

    const int b  = blockIdx.x;
    const int s0 = goff[b], s1 = goff[b + 1];
    const int lane = tid & 63;
    const int wv   = tid >> 6;          // 8 waves
    const int quarter = lane >> 4;      // 4 edges in flight per wave
    const int d4 = lane & 15;           // 4-dim group
    const unsigned short* hbs = reinterpret_cast<const unsigned short*>(hb);

    for (int p = s0 + wv * 4 + quarter; p < s1; p += 32) {
        const uint2 pr = pairs[p];                  // 16 lanes same addr
        const int col = pr.x & 0xFFFF;
        const int rl  = (pr.x >> 16) & 0xFF;
        const float a = __uint_as_float(pr.y);
        const uint2 hv = *reinterpret_cast<const uint2*>(
            hbs + (size_t)col * DIM_OUT + d4 * 4);
        float* ap = &acc[rl * 65 + d4 * 4];
        atomicAdd(ap + 0, a * __uint_as_float(hv.x << 16));
        atomicAdd(ap + 1, a * __uint_as_float(hv.x & 0xffff0000u));
        atomicAdd(ap + 2, a * __uint_as_float(hv.y << 16));
        atomicAdd(ap + 3, a * __uint_as_float(hv.y & 0xffff0000u));
    }
    __syncthreads();

    const int grow0 = b * RPB;
    for (int item = tid; item < RPB * 16; item += RED_THREADS) {
        const int r  = item >> 4;
        const int c4 = item & 15;
        const int grow = grow0 + r;
        if (grow < n_nodes) {
            const float* ap = &acc[r * 65 + c4 * 4];
            *reinterpret_cast<float4*>(out + (size_t)grow * DIM_OUT + c4 * 4) =
                make_float4(ap[0], ap[1], ap[2], ap[3]);
        }
    }
}

// ---------------------------------------------------------------------------
// Fallback scatter (atomics) if constraints not met.
// ---------------------------------------------------------------------------
__global__ __launch_bounds__(256) void gnn_scatter_atomic_kernel(
    const __hip_bfloat16* __restrict__ hb, const int* __restrict__ edge_rows,
    const int* __restrict__ edge_cols, const float* __restrict__ adj_vals,
    float* __restrict__ out, int n_edges)
{
    const long long idx = (long long)blockIdx.x * blockDim.x + threadIdx.x;
    if (idx >= (long long)n_edges * DIM_OUT) return;
    const int e = (int)(idx >> 6);
    const int d = (int)(idx & 63);
    const float v = adj_vals[e] *
        __bfloat162float(hb[(size_t)edge_cols[e] * DIM_OUT + d]);
    atomicAdd(&out[(size_t)edge_rows[e] * DIM_OUT + d], v);
}

extern "C" void kernel_launch(void* const* d_in, const int* in_sizes, int n_in,
                              void* d_out, int out_size, void* d_ws, size_t ws_size,
                              hipStream_t stream)
{
    const float* x         = (const float*)d_in[0];
    const float* W         = (const float*)d_in[1];
    const int*   edge_rows = (const int*)d_in[2];
    const int*   edge_cols = (const int*)d_in[3];
    const float* adj_vals  = (const float*)d_in[4];
    float*       out       = (float*)d_out;

    const int n_nodes = in_sizes[0] / DIM_IN;
    const int n_edges = in_sizes[2];
    const int nb = (n_nodes + RPB - 1) / RPB;

    // workspace layout
    char* ws = (char*)d_ws;
    size_t off = 0;
    __hip_bfloat16* hb = (__hip_bfloat16*)(ws + off);
    off = align256(off + (size_t)n_nodes * DIM_OUT * 2);
    int* ghist = (int*)(ws + off); off = align256(off + (size_t)nb * 4);
    int* goff  = (int*)(ws + off); off = align256(off + ((size_t)nb + 1) * 4);
    int* gcur  = (int*)(ws + off); off = align256(off + (size_t)nb * 4);
    uint2* pairs = (uint2*)(ws + off); off = align256(off + (size_t)n_edges * 8);
    const bool use_bucket = (off <= ws_size) && (n_nodes <= 65536);

    // K1: MFMA dense transform
    {
        const int ntiles = (n_nodes + 15) / 16;
        gnn_gemm_mfma_kernel<<<(ntiles + 3) / 4, 256, 0, stream>>>(
            x, W, hb, n_nodes);
    }

    if (use_bucket) {
        hipMemsetAsync(ghist, 0, (size_t)nb * 4, stream);
        gnn_bucket_hist_kernel<<<256, 256, 0, stream>>>(
            edge_rows, ghist, n_edges, nb);
        gnn_bucket_scan_kernel<<<1, 256, 0, stream>>>(
            ghist, goff, gcur, nb, n_edges);
        gnn_multisplit_kernel<<<(n_edges + MS_EPB - 1) / MS_EPB, 256, 0, stream>>>(
            edge_rows, edge_cols, adj_vals, gcur, pairs, n_edges, nb);
        gnn_reduce_lds_kernel<<<nb, RED_THREADS, 0, stream>>>(
            hb, goff, pairs, out, n_nodes);
    } else {
        hipMemsetAsync(d_out, 0, (size_t)out_size * sizeof(float), stream);
        const long long total = (long long)n_edges * DIM_OUT;
        gnn_scatter_atomic_kernel<<<(int)((total + 255) / 256), 256, 0, stream>>>(
            hb, edge_rows, edge_cols, adj_vals, out, n_edges);
    }
}